// Round 7
// baseline (94.375 us; speedup 1.0000x reference)
//
#include <hip/hip_runtime.h>
#include <math.h>

namespace {
constexpr int BB  = 2048;
constexpr int SS  = 512;
constexpr int TPB = 128;       // 4 steps per thread
constexpr int NSQ = 4;         // balanced norm <= 10.5; /16 -> theta <= 0.66
constexpr float SCV = 0.0625f; // 2^-NSQ
constexpr float LOG2E = 1.44269504f;
}

// fast 1-ulp hardware ops (tolerance is 6e-2; these are ~1e-7 rel)
__device__ __forceinline__ float frcp(float x) { return __builtin_amdgcn_rcpf(x); }
__device__ __forceinline__ float frsq(float x) { return __builtin_amdgcn_rsqf(x); }
__device__ __forceinline__ float flog(float x) {
    return __builtin_amdgcn_logf(x) * 0.69314718056f;
}
__device__ __forceinline__ float fexp(float x) {
    return __builtin_amdgcn_exp2f(x * LOG2E);
}

// full per-step coefficients (output of make_step)
struct Aff {
    float a00, a01, a10, a11;   // 2x2 oscillator block T
    float a20, a21, a22;        // row 2
    float a30, a31, a32, a33;   // row 3
    float c0, c1, c2, c3;       // input vector
};

__device__ __forceinline__ Aff aff_identity() {
    Aff r;
    r.a00 = 1.f; r.a01 = 0.f; r.a10 = 0.f; r.a11 = 1.f;
    r.a20 = 0.f; r.a21 = 0.f; r.a22 = 1.f;
    r.a30 = 0.f; r.a31 = 0.f; r.a32 = 0.f; r.a33 = 1.f;
    r.c0 = 0.f; r.c1 = 0.f; r.c2 = 0.f; r.c3 = 0.f;
    return r;
}

// ---- oscillator (top 2x2) affine scan primitives ----
struct Osc { float a00, a01, a10, a11, c0, c1; };

__device__ __forceinline__ Osc osc_compose(const Osc& s, const Osc& f) {
    Osc r;
    r.a00 = s.a00*f.a00 + s.a01*f.a10;
    r.a01 = s.a00*f.a01 + s.a01*f.a11;
    r.a10 = s.a10*f.a00 + s.a11*f.a10;
    r.a11 = s.a10*f.a01 + s.a11*f.a11;
    r.c0  = s.a00*f.c0 + s.a01*f.c1 + s.c0;
    r.c1  = s.a10*f.c0 + s.a11*f.c1 + s.c1;
    return r;
}
__device__ __forceinline__ Osc osc_shfl_up(const Osc& a, int d) {
    Osc r;
    r.a00 = __shfl_up(a.a00, d, 64); r.a01 = __shfl_up(a.a01, d, 64);
    r.a10 = __shfl_up(a.a10, d, 64); r.a11 = __shfl_up(a.a11, d, 64);
    r.c0  = __shfl_up(a.c0,  d, 64); r.c1  = __shfl_up(a.c1,  d, 64);
    return r;
}
__device__ __forceinline__ Osc osc_sel(const Osc& p, bool ok) {
    Osc r;
    r.a00 = ok ? p.a00 : 1.f; r.a01 = ok ? p.a01 : 0.f;
    r.a10 = ok ? p.a10 : 0.f; r.a11 = ok ? p.a11 : 1.f;
    r.c0  = ok ? p.c0  : 0.f; r.c1  = ok ? p.c1  : 0.f;
    return r;
}
__device__ __forceinline__ void osc_apply(const Osc& m, float& v0, float& v1) {
    const float y0 = m.a00*v0 + m.a01*v1 + m.c0;
    const float y1 = m.a10*v0 + m.a11*v1 + m.c1;
    v0 = y0; v1 = y1;
}

// ---- lower-triangular (bottom 2x2) affine scan primitives ----
struct Low { float l00, l10, l11, c0, c1; };

__device__ __forceinline__ Low low_compose(const Low& s, const Low& f) {
    Low r;
    r.l00 = s.l00*f.l00;
    r.l10 = s.l10*f.l00 + s.l11*f.l10;
    r.l11 = s.l11*f.l11;
    r.c0  = fmaf(s.l00, f.c0, s.c0);
    r.c1  = fmaf(s.l10, f.c0, fmaf(s.l11, f.c1, s.c1));
    return r;
}
__device__ __forceinline__ Low low_shfl_up(const Low& a, int d) {
    Low r;
    r.l00 = __shfl_up(a.l00, d, 64); r.l10 = __shfl_up(a.l10, d, 64);
    r.l11 = __shfl_up(a.l11, d, 64);
    r.c0  = __shfl_up(a.c0,  d, 64); r.c1  = __shfl_up(a.c1,  d, 64);
    return r;
}
__device__ __forceinline__ Low low_sel(const Low& p, bool ok) {
    Low r;
    r.l00 = ok ? p.l00 : 1.f; r.l10 = ok ? p.l10 : 0.f;
    r.l11 = ok ? p.l11 : 1.f;
    r.c0  = ok ? p.c0  : 0.f; r.c1  = ok ? p.c1  : 0.f;
    return r;
}
__device__ __forceinline__ void low_apply(const Low& m, float& x2, float& x3) {
    const float y2 = fmaf(m.l00, x2, m.c0);
    const float y3 = m.l10*x2 + m.l11*x3 + m.c1;
    x2 = y2; x3 = y3;
}

// one discretization step:
//   E = expm(M), M = balanced A*dt. T,C blocks: degree-6 Taylor on M/16;
//   L block: CLOSED FORM at base scale (2 exps; rates wave-uniform), then
//   4 squarings of the full block-triangular structure.
//   G1 = phi1(M) g = M^{-1}(E - I) g   (exact identity, no series)
//   G2 = phi2(M) g = M^{-1}(G1 - g)
__device__ __forceinline__ Aff make_step(
    float Iss, float dt, float uk, float uk1,
    float sprod, float aprod, float tau_out, float Aloop1,
    float wsf, float wdf, float rwsf, float rwdf, float CWD)
{
    const float rI  = frcp(Iss);
    const float s   = sprod * rI;                 // tin + tml
    const float idn = frcp(s * tau_out);
    const float a   = fmaf(aprod, rI, tau_out) * idn;
    const float w2  = Aloop1 * idn;
    const float iw  = frsq(w2);
    const float w   = w2 * iw;

    const float dts = dt * SCV;
    const float f00 = -a * dts;
    const float f01 = -w * dts;
    const float f10 =  w * dts;
    const float f21 =  wsf * dts;
    const float f22 = -f21;
    const float f32 =  wdf * dts;
    const float f33 = -f32;

    // T,C blocks: degree-6 Taylor (Horner); theta<=0.66 -> trunc ~1e-5.
    // (C-recurrence only reads T-series + f-constants, never the L-series.)
    float t00 = fmaf(f00, 1.0f/6.0f, 1.0f), t01 = f01 * (1.0f/6.0f);
    float t10 = f10 * (1.0f/6.0f),          t11 = 1.0f;
    float c00 = 0.0f, c01 = f21 * (1.0f/6.0f), c10 = 0.0f, c11 = 0.0f;
#pragma unroll
    for (int m = 5; m >= 1; --m) {
        const float rm = 1.0f / (float)m;  // folds to literal under unroll
        const float p00 = f00*t00 + f01*t10;
        const float p01 = f00*t01 + f01*t11;
        const float p10 = f10*t00;
        const float p11 = f10*t01;
        const float q00 = f21*t10 + f22*c00;
        const float q01 = f21*t11 + f22*c01;
        const float q10 = f32*c00 + f33*c10;
        const float q11 = f32*c01 + f33*c11;
        t00 = fmaf(p00, rm, 1.0f); t01 = p01*rm;
        t10 = p10*rm;              t11 = fmaf(p11, rm, 1.0f);
        c00 = q00*rm; c01 = q01*rm; c10 = q10*rm; c11 = q11*rm;
    }

    // L block closed form at base scale (exact):
    //   l00 = e^{f22}, l11 = e^{f33}, l10 = CWD*(l00-l11),
    //   CWD = wdf/(wdf-wsf)  (wave-uniform; wsf != wdf by construction)
    float l00 = fexp(f22);
    float l11 = fexp(f33);
    float l10 = CWD * (l00 - l11);

    // 4 squarings of the full structure
#pragma unroll
    for (int i = 0; i < NSQ; ++i) {
        const float p00 = t00*t00 + t01*t10;
        const float p01 = t00*t01 + t01*t11;
        const float p10 = t10*t00 + t11*t10;
        const float p11 = t10*t01 + t11*t11;
        const float q00 = c00*t00 + c01*t10 + l00*c00;
        const float q01 = c00*t01 + c01*t11 + l00*c01;
        const float q10 = c10*t00 + c11*t10 + l10*c00 + l11*c10;
        const float q11 = c10*t01 + c11*t11 + l10*c01 + l11*c11;
        const float m00 = l00*l00;
        const float m10 = l10*l00 + l11*l10;
        const float m11 = l11*l11;
        t00 = p00; t01 = p01; t10 = p10; t11 = p11;
        c00 = q00; c01 = q01; c10 = q10; c11 = q11;
        l00 = m00; l10 = m10; l11 = m11;
    }

    // phi1/phi2 via exact back-substitution solves (balanced space)
    const float aw  = a * iw;           // a/w
    const float rdt = frcp(dt);
    const float rF  = iw * rdt;         // 1/(w dt)
    const float rS  = rwsf * rdt;       // 1/(wsf dt)
    const float rD  = rwdf * rdt;       // 1/(wdf dt)
    const float wS  = w * rwsf;         // w/wsf
    const float wD  = w * rwdf;         // w/wdf
    const float g0u = w * dt;

    // G1 = M^{-1}(E-I)g  (balanced)
    const float y0 = t10;
    const float y1 = -fmaf(aw, t10, t00 - 1.0f);
    const float y2 = fmaf(-wS, c00, y1);
    const float y3 = fmaf(-wD, c10, y2);
    // G2 = M^{-1}(G1 - g)  (balanced)
    const float s0 = y0 - g0u;
    const float z0 = y1 * rF;
    const float z1 = -fmaf(aw, z0, rF * s0);
    const float z2 = fmaf(-y2, rS, z1);
    const float z3 = fmaf(-y3, rD, z2);

    // unbalance: Ad = D E D^-1, D = diag(w,1,1,1); G *= D
    Aff r;
    r.a00 = t00;      r.a01 = w * t01;
    r.a10 = t10 * iw; r.a11 = t11;
    r.a20 = c00 * iw; r.a21 = c01; r.a22 = l00;
    r.a30 = c10 * iw; r.a31 = c11; r.a32 = l10; r.a33 = l11;
    const float G10 = w * y0, G20 = w * z0;
    // c = G1*uk + G2*(uk1-uk)   (== Bd*uk + Bt*uk1)
    const float du = uk1 - uk;
    r.c0 = fmaf(G10, uk, G20 * du);
    r.c1 = fmaf(y1,  uk, z1 * du);
    r.c2 = fmaf(y2,  uk, z2 * du);
    r.c3 = fmaf(y3,  uk, z3 * du);
    return r;
}

__global__ __launch_bounds__(TPB, 4) void pbw_kernel(
    const float* __restrict__ it_eff,
    const float* __restrict__ ts,
    const float* __restrict__ p_tin_prod,
    const float* __restrict__ p_tmil_raw,
    const float* __restrict__ p_aamp_raw,
    const float* __restrict__ p_aloop_raw,
    const float* __restrict__ p_tout_raw,
    const float* __restrict__ p_tsf_raw,
    const float* __restrict__ p_tdiff_raw,
    float* __restrict__ out)
{
    __shared__ float swcA[6];       // wave-0 oscillator composite
    __shared__ float swcB[5];       // wave-0 low composite
    __shared__ float sy[SS + 4];    // output staging (+4 pad for tail thread)

    const int b = blockIdx.x;
    const int t = threadIdx.x;
    const int lane = t & 63;
    const int wv = t >> 6;

    // derived scalar params (wave-uniform)
    const float tin_prod  = p_tin_prod[0];
    const float tmil_prod = log1pf(expf(p_tmil_raw[0]));
    const float Aamp1     = 1.0f / log1pf(expf(p_aamp_raw[0])) + 1.0f;
    const float Aloop1    = 1.0f / log1pf(expf(p_aloop_raw[0])) + 1.0f;
    const float tau_out   = log1pf(expf(p_tout_raw[0]));
    const float sp_sf     = log1pf(expf(p_tsf_raw[0]));
    const float sp_df     = log1pf(expf(p_tdiff_raw[0]));
    const float wsf       = 1.0f / sp_sf;
    const float wdf       = 1.0f / sp_df;
    const float CWD       = wdf / (wdf - wsf);            // wave-uniform
    const float sprod = tin_prod + tmil_prod;             // (tin+tml)*I
    const float aprod = fmaf(Aamp1, tmil_prod, tin_prod); // (tin+Aamp1*tml)*I

    const float* rowI = it_eff + (size_t)b * SS;
    const float* rowT = ts     + (size_t)b * SS;

    // thread t owns steps k = 4t .. 4t+3 (last thread: 3 real + identity)
    const int k0 = 4 * t;
    const float4 I4 = *(const float4*)(rowI + k0);
    const float4 T4 = *(const float4*)(rowT + k0);
    const bool last = (t == TPB - 1);
    const float I_4 = last ? 1.0f : rowI[k0 + 4];
    const float T_4 = last ? (T4.w + 1e-4f) : rowT[k0 + 4];

    const float u_0 = flog(I4.x);
    const float u_1 = flog(I4.y);
    const float u_2 = flog(I4.z);
    const float u_3 = flog(I4.w);
    const float u_4 = flog(I_4);
    const float u0  = flog(rowI[0]);   // broadcast load

    Aff m0 = make_step(I4.y, T4.y - T4.x, u_0, u_1,
                       sprod, aprod, tau_out, Aloop1, wsf, wdf, sp_sf, sp_df, CWD);
    Aff m1 = make_step(I4.z, T4.z - T4.y, u_1, u_2,
                       sprod, aprod, tau_out, Aloop1, wsf, wdf, sp_sf, sp_df, CWD);
    Aff m2 = make_step(I4.w, T4.w - T4.z, u_2, u_3,
                       sprod, aprod, tau_out, Aloop1, wsf, wdf, sp_sf, sp_df, CWD);
    Aff m3 = make_step(I_4, T_4 - T4.w, u_3, u_4,
                       sprod, aprod, tau_out, Aloop1, wsf, wdf, sp_sf, sp_df, CWD);
    if (last) m3 = aff_identity();

    // ================= Phase A: oscillator (x0,x1) scan =================
    const Osc s0 = {m0.a00, m0.a01, m0.a10, m0.a11, m0.c0, m0.c1};
    const Osc s1 = {m1.a00, m1.a01, m1.a10, m1.a11, m1.c0, m1.c1};
    const Osc s2 = {m2.a00, m2.a01, m2.a10, m2.a11, m2.c0, m2.c1};
    const Osc s3 = {m3.a00, m3.a01, m3.a10, m3.a11, m3.c0, m3.c1};

    Osc oc = osc_compose(osc_compose(s3, s2), osc_compose(s1, s0));
#pragma unroll
    for (int d = 1; d < 64; d <<= 1) {
        Osc p = osc_shfl_up(oc, d);
        p = osc_sel(p, lane >= d);
        oc = osc_compose(oc, p);
    }
    if (wv == 0 && lane == 63) {
        swcA[0]=oc.a00; swcA[1]=oc.a01; swcA[2]=oc.a10; swcA[3]=oc.a11;
        swcA[4]=oc.c0;  swcA[5]=oc.c1;
    }
    __syncthreads();

    float v0 = 0.0f, v1 = u0;
    if (wv == 1) {
        Osc wm = {swcA[0], swcA[1], swcA[2], swcA[3], swcA[4], swcA[5]};
        osc_apply(wm, v0, v1);
    }
    Osc oex = osc_shfl_up(oc, 1);
    oex = osc_sel(oex, lane >= 1);
    osc_apply(oex, v0, v1);

    // v at the 4 local step-starts
    const float va0 = v0, vb0 = v1;
    osc_apply(s0, v0, v1); const float va1 = v0, vb1 = v1;
    osc_apply(s1, v0, v1); const float va2 = v0, vb2 = v1;
    osc_apply(s2, v0, v1); const float va3 = v0, vb3 = v1;

    // ================= Phase B: lower-tri (x2,x3) scan =================
    const Low b0 = {m0.a22, m0.a32, m0.a33,
                    m0.a20*va0 + m0.a21*vb0 + m0.c2,
                    m0.a30*va0 + m0.a31*vb0 + m0.c3};
    const Low b1 = {m1.a22, m1.a32, m1.a33,
                    m1.a20*va1 + m1.a21*vb1 + m1.c2,
                    m1.a30*va1 + m1.a31*vb1 + m1.c3};
    const Low b2 = {m2.a22, m2.a32, m2.a33,
                    m2.a20*va2 + m2.a21*vb2 + m2.c2,
                    m2.a30*va2 + m2.a31*vb2 + m2.c3};
    const Low b3 = {m3.a22, m3.a32, m3.a33,
                    m3.a20*va3 + m3.a21*vb3 + m3.c2,
                    m3.a30*va3 + m3.a31*vb3 + m3.c3};

    Low lc = low_compose(low_compose(b3, b2), low_compose(b1, b0));
#pragma unroll
    for (int d = 1; d < 64; d <<= 1) {
        Low p = low_shfl_up(lc, d);
        p = low_sel(p, lane >= d);
        lc = low_compose(lc, p);
    }
    if (wv == 0 && lane == 63) {
        swcB[0]=lc.l00; swcB[1]=lc.l10; swcB[2]=lc.l11;
        swcB[3]=lc.c0;  swcB[4]=lc.c1;
    }
    __syncthreads();

    float x2 = u0, x3 = u0;
    if (wv == 1) {
        Low wm = {swcB[0], swcB[1], swcB[2], swcB[3], swcB[4]};
        low_apply(wm, x2, x3);
    }
    Low lex = low_shfl_up(lc, 1);
    lex = low_sel(lex, lane >= 1);
    low_apply(lex, x2, x3);

    // replay: y = x3 after each local step
    low_apply(b0, x2, x3); sy[k0 + 1] = x3;
    low_apply(b1, x2, x3); sy[k0 + 2] = x3;
    low_apply(b2, x2, x3); sy[k0 + 3] = x3;
    low_apply(b3, x2, x3); sy[k0 + 4] = x3;   // k0+4==512 lands in pad
    if (t == 0) sy[0] = u0;

    __syncthreads();

    // coalesced float4 store
    float4* po = (float4*)(out + (size_t)b * SS);
    po[t] = *(const float4*)&sy[4 * t];
}

extern "C" void kernel_launch(void* const* d_in, const int* in_sizes, int n_in,
                              void* d_out, int out_size, void* d_ws, size_t ws_size,
                              hipStream_t stream) {
    const float* it_eff = (const float*)d_in[0];
    const float* ts     = (const float*)d_in[1];
    const float* p2 = (const float*)d_in[2];
    const float* p3 = (const float*)d_in[3];
    const float* p4 = (const float*)d_in[4];
    const float* p5 = (const float*)d_in[5];
    const float* p6 = (const float*)d_in[6];
    const float* p7 = (const float*)d_in[7];
    const float* p8 = (const float*)d_in[8];
    float* out = (float*)d_out;

    pbw_kernel<<<dim3(BB), dim3(TPB), 0, stream>>>(
        it_eff, ts, p2, p3, p4, p5, p6, p7, p8, out);
}

// Round 8
// 88.104 us; speedup vs baseline: 1.0712x; 1.0712x over previous
//
#include <hip/hip_runtime.h>
#include <math.h>

namespace {
constexpr int BB  = 2048;
constexpr int SS  = 512;
constexpr int TPB = 128;       // 4 steps per thread
constexpr int NSQ = 4;         // balanced norm <= 10.5; /16 -> theta <= 0.66
constexpr float SCV = 0.0625f; // 2^-NSQ
constexpr float LOG2E = 1.44269504f;
}

// fast 1-ulp hardware ops (tolerance is 6e-2; these are ~1e-7 rel)
__device__ __forceinline__ float frcp(float x) { return __builtin_amdgcn_rcpf(x); }
__device__ __forceinline__ float frsq(float x) { return __builtin_amdgcn_rsqf(x); }
__device__ __forceinline__ float flog(float x) {
    return __builtin_amdgcn_logf(x) * 0.69314718056f;
}
__device__ __forceinline__ float fexp(float x) {
    return __builtin_amdgcn_exp2f(x * LOG2E);
}

// full per-step coefficients (output of make_step)
struct Aff {
    float a00, a01, a10, a11;   // 2x2 oscillator block T
    float a20, a21, a22;        // row 2
    float a30, a31, a32, a33;   // row 3
    float c0, c1, c2, c3;       // input vector
};

__device__ __forceinline__ Aff aff_identity() {
    Aff r;
    r.a00 = 1.f; r.a01 = 0.f; r.a10 = 0.f; r.a11 = 1.f;
    r.a20 = 0.f; r.a21 = 0.f; r.a22 = 1.f;
    r.a30 = 0.f; r.a31 = 0.f; r.a32 = 0.f; r.a33 = 1.f;
    r.c0 = 0.f; r.c1 = 0.f; r.c2 = 0.f; r.c3 = 0.f;
    return r;
}

// ---- oscillator (top 2x2) affine scan primitives ----
struct Osc { float a00, a01, a10, a11, c0, c1; };

__device__ __forceinline__ Osc osc_compose(const Osc& s, const Osc& f) {
    Osc r;
    r.a00 = s.a00*f.a00 + s.a01*f.a10;
    r.a01 = s.a00*f.a01 + s.a01*f.a11;
    r.a10 = s.a10*f.a00 + s.a11*f.a10;
    r.a11 = s.a10*f.a01 + s.a11*f.a11;
    r.c0  = s.a00*f.c0 + s.a01*f.c1 + s.c0;
    r.c1  = s.a10*f.c0 + s.a11*f.c1 + s.c1;
    return r;
}
__device__ __forceinline__ Osc osc_shfl_up(const Osc& a, int d) {
    Osc r;
    r.a00 = __shfl_up(a.a00, d, 64); r.a01 = __shfl_up(a.a01, d, 64);
    r.a10 = __shfl_up(a.a10, d, 64); r.a11 = __shfl_up(a.a11, d, 64);
    r.c0  = __shfl_up(a.c0,  d, 64); r.c1  = __shfl_up(a.c1,  d, 64);
    return r;
}
__device__ __forceinline__ Osc osc_sel(const Osc& p, bool ok) {
    Osc r;
    r.a00 = ok ? p.a00 : 1.f; r.a01 = ok ? p.a01 : 0.f;
    r.a10 = ok ? p.a10 : 0.f; r.a11 = ok ? p.a11 : 1.f;
    r.c0  = ok ? p.c0  : 0.f; r.c1  = ok ? p.c1  : 0.f;
    return r;
}
__device__ __forceinline__ void osc_apply(const Osc& m, float& v0, float& v1) {
    const float y0 = m.a00*v0 + m.a01*v1 + m.c0;
    const float y1 = m.a10*v0 + m.a11*v1 + m.c1;
    v0 = y0; v1 = y1;
}

// ---- lower-triangular (bottom 2x2) affine scan primitives ----
struct Low { float l00, l10, l11, c0, c1; };

__device__ __forceinline__ Low low_compose(const Low& s, const Low& f) {
    Low r;
    r.l00 = s.l00*f.l00;
    r.l10 = s.l10*f.l00 + s.l11*f.l10;
    r.l11 = s.l11*f.l11;
    r.c0  = fmaf(s.l00, f.c0, s.c0);
    r.c1  = fmaf(s.l10, f.c0, fmaf(s.l11, f.c1, s.c1));
    return r;
}
__device__ __forceinline__ Low low_shfl_up(const Low& a, int d) {
    Low r;
    r.l00 = __shfl_up(a.l00, d, 64); r.l10 = __shfl_up(a.l10, d, 64);
    r.l11 = __shfl_up(a.l11, d, 64);
    r.c0  = __shfl_up(a.c0,  d, 64); r.c1  = __shfl_up(a.c1,  d, 64);
    return r;
}
__device__ __forceinline__ Low low_sel(const Low& p, bool ok) {
    Low r;
    r.l00 = ok ? p.l00 : 1.f; r.l10 = ok ? p.l10 : 0.f;
    r.l11 = ok ? p.l11 : 1.f;
    r.c0  = ok ? p.c0  : 0.f; r.c1  = ok ? p.c1  : 0.f;
    return r;
}
__device__ __forceinline__ void low_apply(const Low& m, float& x2, float& x3) {
    const float y2 = fmaf(m.l00, x2, m.c0);
    const float y3 = m.l10*x2 + m.l11*x3 + m.c1;
    x2 = y2; x3 = y3;
}

// one discretization step:
//   E = expm(M), M = balanced A*dt. T,C blocks: degree-6 Taylor on M/16;
//   L block: CLOSED FORM at base scale (2 exps; rates wave-uniform), then
//   4 squarings of the full block-triangular structure.
//   G1 = phi1(M) g = M^{-1}(E - I) g   (exact identity, no series)
//   G2 = phi2(M) g = M^{-1}(G1 - g)
__device__ __forceinline__ Aff make_step(
    float Iss, float dt, float uk, float uk1,
    float sprod, float aprod, float tau_out, float Aloop1,
    float wsf, float wdf, float rwsf, float rwdf, float CWD)
{
    const float rI  = frcp(Iss);
    const float s   = sprod * rI;                 // tin + tml
    const float idn = frcp(s * tau_out);
    const float a   = fmaf(aprod, rI, tau_out) * idn;
    const float w2  = Aloop1 * idn;
    const float iw  = frsq(w2);
    const float w   = w2 * iw;

    const float dts = dt * SCV;
    const float f00 = -a * dts;
    const float f01 = -w * dts;
    const float f10 =  w * dts;
    const float f21 =  wsf * dts;
    const float f22 = -f21;
    const float f32 =  wdf * dts;
    const float f33 = -f32;

    // T,C blocks: degree-6 Taylor (Horner); theta<=0.66 -> trunc ~1e-5.
    // (C-recurrence only reads T-series + f-constants, never the L-series.)
    float t00 = fmaf(f00, 1.0f/6.0f, 1.0f), t01 = f01 * (1.0f/6.0f);
    float t10 = f10 * (1.0f/6.0f),          t11 = 1.0f;
    float c00 = 0.0f, c01 = f21 * (1.0f/6.0f), c10 = 0.0f, c11 = 0.0f;
#pragma unroll
    for (int m = 5; m >= 1; --m) {
        const float rm = 1.0f / (float)m;  // folds to literal under unroll
        const float p00 = f00*t00 + f01*t10;
        const float p01 = f00*t01 + f01*t11;
        const float p10 = f10*t00;
        const float p11 = f10*t01;
        const float q00 = f21*t10 + f22*c00;
        const float q01 = f21*t11 + f22*c01;
        const float q10 = f32*c00 + f33*c10;
        const float q11 = f32*c01 + f33*c11;
        t00 = fmaf(p00, rm, 1.0f); t01 = p01*rm;
        t10 = p10*rm;              t11 = fmaf(p11, rm, 1.0f);
        c00 = q00*rm; c01 = q01*rm; c10 = q10*rm; c11 = q11*rm;
    }

    // L block closed form at base scale (exact):
    //   l00 = e^{f22}, l11 = e^{f33}, l10 = CWD*(l00-l11),
    //   CWD = wdf/(wdf-wsf)  (wave-uniform; wsf != wdf by construction)
    float l00 = fexp(f22);
    float l11 = fexp(f33);
    float l10 = CWD * (l00 - l11);

    // 4 squarings of the full structure
#pragma unroll
    for (int i = 0; i < NSQ; ++i) {
        const float p00 = t00*t00 + t01*t10;
        const float p01 = t00*t01 + t01*t11;
        const float p10 = t10*t00 + t11*t10;
        const float p11 = t10*t01 + t11*t11;
        const float q00 = c00*t00 + c01*t10 + l00*c00;
        const float q01 = c00*t01 + c01*t11 + l00*c01;
        const float q10 = c10*t00 + c11*t10 + l10*c00 + l11*c10;
        const float q11 = c10*t01 + c11*t11 + l10*c01 + l11*c11;
        const float m00 = l00*l00;
        const float m10 = l10*l00 + l11*l10;
        const float m11 = l11*l11;
        t00 = p00; t01 = p01; t10 = p10; t11 = p11;
        c00 = q00; c01 = q01; c10 = q10; c11 = q11;
        l00 = m00; l10 = m10; l11 = m11;
    }

    // phi1/phi2 via exact back-substitution solves (balanced space)
    const float aw  = a * iw;           // a/w
    const float rdt = frcp(dt);
    const float rF  = iw * rdt;         // 1/(w dt)
    const float rS  = rwsf * rdt;       // 1/(wsf dt)
    const float rD  = rwdf * rdt;       // 1/(wdf dt)
    const float wS  = w * rwsf;         // w/wsf
    const float wD  = w * rwdf;         // w/wdf
    const float g0u = w * dt;

    // G1 = M^{-1}(E-I)g  (balanced)
    const float y0 = t10;
    const float y1 = -fmaf(aw, t10, t00 - 1.0f);
    const float y2 = fmaf(-wS, c00, y1);
    const float y3 = fmaf(-wD, c10, y2);
    // G2 = M^{-1}(G1 - g)  (balanced)
    const float s0 = y0 - g0u;
    const float z0 = y1 * rF;
    const float z1 = -fmaf(aw, z0, rF * s0);
    const float z2 = fmaf(-y2, rS, z1);
    const float z3 = fmaf(-y3, rD, z2);

    // unbalance: Ad = D E D^-1, D = diag(w,1,1,1); G *= D
    Aff r;
    r.a00 = t00;      r.a01 = w * t01;
    r.a10 = t10 * iw; r.a11 = t11;
    r.a20 = c00 * iw; r.a21 = c01; r.a22 = l00;
    r.a30 = c10 * iw; r.a31 = c11; r.a32 = l10; r.a33 = l11;
    const float G10 = w * y0, G20 = w * z0;
    // c = G1*uk + G2*(uk1-uk)   (== Bd*uk + Bt*uk1)
    const float du = uk1 - uk;
    r.c0 = fmaf(G10, uk, G20 * du);
    r.c1 = fmaf(y1,  uk, z1 * du);
    r.c2 = fmaf(y2,  uk, z2 * du);
    r.c3 = fmaf(y3,  uk, z3 * du);
    return r;
}

__global__ __launch_bounds__(TPB) void pbw_kernel(
    const float* __restrict__ it_eff,
    const float* __restrict__ ts,
    const float* __restrict__ p_tin_prod,
    const float* __restrict__ p_tmil_raw,
    const float* __restrict__ p_aamp_raw,
    const float* __restrict__ p_aloop_raw,
    const float* __restrict__ p_tout_raw,
    const float* __restrict__ p_tsf_raw,
    const float* __restrict__ p_tdiff_raw,
    float* __restrict__ out)
{
    __shared__ float swcA[6];       // wave-0 oscillator composite
    __shared__ float swcB[5];       // wave-0 low composite
    __shared__ float sy[SS + 4];    // output staging (+4 pad for tail thread)

    const int b = blockIdx.x;
    const int t = threadIdx.x;
    const int lane = t & 63;
    const int wv = t >> 6;

    // derived scalar params (wave-uniform)
    const float tin_prod  = p_tin_prod[0];
    const float tmil_prod = log1pf(expf(p_tmil_raw[0]));
    const float Aamp1     = 1.0f / log1pf(expf(p_aamp_raw[0])) + 1.0f;
    const float Aloop1    = 1.0f / log1pf(expf(p_aloop_raw[0])) + 1.0f;
    const float tau_out   = log1pf(expf(p_tout_raw[0]));
    const float sp_sf     = log1pf(expf(p_tsf_raw[0]));
    const float sp_df     = log1pf(expf(p_tdiff_raw[0]));
    const float wsf       = 1.0f / sp_sf;
    const float wdf       = 1.0f / sp_df;
    const float CWD       = wdf / (wdf - wsf);            // wave-uniform
    const float sprod = tin_prod + tmil_prod;             // (tin+tml)*I
    const float aprod = fmaf(Aamp1, tmil_prod, tin_prod); // (tin+Aamp1*tml)*I

    const float* rowI = it_eff + (size_t)b * SS;
    const float* rowT = ts     + (size_t)b * SS;

    // thread t owns steps k = 4t .. 4t+3 (last thread: 3 real + identity)
    const int k0 = 4 * t;
    const float4 I4 = *(const float4*)(rowI + k0);
    const float4 T4 = *(const float4*)(rowT + k0);
    const bool last = (t == TPB - 1);
    const float I_4 = last ? 1.0f : rowI[k0 + 4];
    const float T_4 = last ? (T4.w + 1e-4f) : rowT[k0 + 4];

    const float u_0 = flog(I4.x);
    const float u_1 = flog(I4.y);
    const float u_2 = flog(I4.z);
    const float u_3 = flog(I4.w);
    const float u_4 = flog(I_4);
    const float u0  = flog(rowI[0]);   // broadcast load

    Aff m0 = make_step(I4.y, T4.y - T4.x, u_0, u_1,
                       sprod, aprod, tau_out, Aloop1, wsf, wdf, sp_sf, sp_df, CWD);
    Aff m1 = make_step(I4.z, T4.z - T4.y, u_1, u_2,
                       sprod, aprod, tau_out, Aloop1, wsf, wdf, sp_sf, sp_df, CWD);
    Aff m2 = make_step(I4.w, T4.w - T4.z, u_2, u_3,
                       sprod, aprod, tau_out, Aloop1, wsf, wdf, sp_sf, sp_df, CWD);
    Aff m3 = make_step(I_4, T_4 - T4.w, u_3, u_4,
                       sprod, aprod, tau_out, Aloop1, wsf, wdf, sp_sf, sp_df, CWD);
    if (last) m3 = aff_identity();

    // ================= Phase A: oscillator (x0,x1) scan =================
    const Osc s0 = {m0.a00, m0.a01, m0.a10, m0.a11, m0.c0, m0.c1};
    const Osc s1 = {m1.a00, m1.a01, m1.a10, m1.a11, m1.c0, m1.c1};
    const Osc s2 = {m2.a00, m2.a01, m2.a10, m2.a11, m2.c0, m2.c1};
    const Osc s3 = {m3.a00, m3.a01, m3.a10, m3.a11, m3.c0, m3.c1};

    Osc oc = osc_compose(osc_compose(s3, s2), osc_compose(s1, s0));
#pragma unroll
    for (int d = 1; d < 64; d <<= 1) {
        Osc p = osc_shfl_up(oc, d);
        p = osc_sel(p, lane >= d);
        oc = osc_compose(oc, p);
    }
    if (wv == 0 && lane == 63) {
        swcA[0]=oc.a00; swcA[1]=oc.a01; swcA[2]=oc.a10; swcA[3]=oc.a11;
        swcA[4]=oc.c0;  swcA[5]=oc.c1;
    }
    __syncthreads();

    float v0 = 0.0f, v1 = u0;
    if (wv == 1) {
        Osc wm = {swcA[0], swcA[1], swcA[2], swcA[3], swcA[4], swcA[5]};
        osc_apply(wm, v0, v1);
    }
    Osc oex = osc_shfl_up(oc, 1);
    oex = osc_sel(oex, lane >= 1);
    osc_apply(oex, v0, v1);

    // v at the 4 local step-starts
    const float va0 = v0, vb0 = v1;
    osc_apply(s0, v0, v1); const float va1 = v0, vb1 = v1;
    osc_apply(s1, v0, v1); const float va2 = v0, vb2 = v1;
    osc_apply(s2, v0, v1); const float va3 = v0, vb3 = v1;

    // ================= Phase B: lower-tri (x2,x3) scan =================
    const Low b0 = {m0.a22, m0.a32, m0.a33,
                    m0.a20*va0 + m0.a21*vb0 + m0.c2,
                    m0.a30*va0 + m0.a31*vb0 + m0.c3};
    const Low b1 = {m1.a22, m1.a32, m1.a33,
                    m1.a20*va1 + m1.a21*vb1 + m1.c2,
                    m1.a30*va1 + m1.a31*vb1 + m1.c3};
    const Low b2 = {m2.a22, m2.a32, m2.a33,
                    m2.a20*va2 + m2.a21*vb2 + m2.c2,
                    m2.a30*va2 + m2.a31*vb2 + m2.c3};
    const Low b3 = {m3.a22, m3.a32, m3.a33,
                    m3.a20*va3 + m3.a21*vb3 + m3.c2,
                    m3.a30*va3 + m3.a31*vb3 + m3.c3};

    Low lc = low_compose(low_compose(b3, b2), low_compose(b1, b0));
#pragma unroll
    for (int d = 1; d < 64; d <<= 1) {
        Low p = low_shfl_up(lc, d);
        p = low_sel(p, lane >= d);
        lc = low_compose(lc, p);
    }
    if (wv == 0 && lane == 63) {
        swcB[0]=lc.l00; swcB[1]=lc.l10; swcB[2]=lc.l11;
        swcB[3]=lc.c0;  swcB[4]=lc.c1;
    }
    __syncthreads();

    float x2 = u0, x3 = u0;
    if (wv == 1) {
        Low wm = {swcB[0], swcB[1], swcB[2], swcB[3], swcB[4]};
        low_apply(wm, x2, x3);
    }
    Low lex = low_shfl_up(lc, 1);
    lex = low_sel(lex, lane >= 1);
    low_apply(lex, x2, x3);

    // replay: y = x3 after each local step
    low_apply(b0, x2, x3); sy[k0 + 1] = x3;
    low_apply(b1, x2, x3); sy[k0 + 2] = x3;
    low_apply(b2, x2, x3); sy[k0 + 3] = x3;
    low_apply(b3, x2, x3); sy[k0 + 4] = x3;   // k0+4==512 lands in pad
    if (t == 0) sy[0] = u0;

    __syncthreads();

    // coalesced float4 store
    float4* po = (float4*)(out + (size_t)b * SS);
    po[t] = *(const float4*)&sy[4 * t];
}

extern "C" void kernel_launch(void* const* d_in, const int* in_sizes, int n_in,
                              void* d_out, int out_size, void* d_ws, size_t ws_size,
                              hipStream_t stream) {
    const float* it_eff = (const float*)d_in[0];
    const float* ts     = (const float*)d_in[1];
    const float* p2 = (const float*)d_in[2];
    const float* p3 = (const float*)d_in[3];
    const float* p4 = (const float*)d_in[4];
    const float* p5 = (const float*)d_in[5];
    const float* p6 = (const float*)d_in[6];
    const float* p7 = (const float*)d_in[7];
    const float* p8 = (const float*)d_in[8];
    float* out = (float*)d_out;

    pbw_kernel<<<dim3(BB), dim3(TPB), 0, stream>>>(
        it_eff, ts, p2, p3, p4, p5, p6, p7, p8, out);
}

// Round 9
// 86.922 us; speedup vs baseline: 1.0858x; 1.0136x over previous
//
#include <hip/hip_runtime.h>
#include <math.h>

namespace {
constexpr int BB  = 2048;
constexpr int SS  = 512;
constexpr int TPB = 128;       // 4 steps per thread
constexpr int NSQ = 4;         // balanced norm <= 10.5; /16 -> theta <= 0.66
constexpr float SCV = 0.0625f; // 2^-NSQ
constexpr float LOG2E = 1.44269504f;
}

// fast 1-ulp hardware ops (tolerance is 6e-2; these are ~1e-7 rel)
__device__ __forceinline__ float frcp(float x) { return __builtin_amdgcn_rcpf(x); }
__device__ __forceinline__ float frsq(float x) { return __builtin_amdgcn_rsqf(x); }
__device__ __forceinline__ float flog(float x) {
    return __builtin_amdgcn_logf(x) * 0.69314718056f;
}
__device__ __forceinline__ float fexp2(float x) {
    return __builtin_amdgcn_exp2f(x);
}

// full per-step coefficients (output of make_step)
struct Aff {
    float a00, a01, a10, a11;   // 2x2 oscillator block T
    float a20, a21, a22;        // row 2
    float a30, a31, a32, a33;   // row 3
    float c0, c1, c2, c3;       // input vector
};

__device__ __forceinline__ Aff aff_identity() {
    Aff r;
    r.a00 = 1.f; r.a01 = 0.f; r.a10 = 0.f; r.a11 = 1.f;
    r.a20 = 0.f; r.a21 = 0.f; r.a22 = 1.f;
    r.a30 = 0.f; r.a31 = 0.f; r.a32 = 0.f; r.a33 = 1.f;
    r.c0 = 0.f; r.c1 = 0.f; r.c2 = 0.f; r.c3 = 0.f;
    return r;
}

// ---- oscillator (top 2x2) affine scan primitives ----
struct Osc { float a00, a01, a10, a11, c0, c1; };

__device__ __forceinline__ Osc osc_compose(const Osc& s, const Osc& f) {
    Osc r;
    r.a00 = s.a00*f.a00 + s.a01*f.a10;
    r.a01 = s.a00*f.a01 + s.a01*f.a11;
    r.a10 = s.a10*f.a00 + s.a11*f.a10;
    r.a11 = s.a10*f.a01 + s.a11*f.a11;
    r.c0  = s.a00*f.c0 + s.a01*f.c1 + s.c0;
    r.c1  = s.a10*f.c0 + s.a11*f.c1 + s.c1;
    return r;
}
__device__ __forceinline__ Osc osc_shfl_up(const Osc& a, int d) {
    Osc r;
    r.a00 = __shfl_up(a.a00, d, 64); r.a01 = __shfl_up(a.a01, d, 64);
    r.a10 = __shfl_up(a.a10, d, 64); r.a11 = __shfl_up(a.a11, d, 64);
    r.c0  = __shfl_up(a.c0,  d, 64); r.c1  = __shfl_up(a.c1,  d, 64);
    return r;
}
__device__ __forceinline__ Osc osc_sel(const Osc& p, bool ok) {
    Osc r;
    r.a00 = ok ? p.a00 : 1.f; r.a01 = ok ? p.a01 : 0.f;
    r.a10 = ok ? p.a10 : 0.f; r.a11 = ok ? p.a11 : 1.f;
    r.c0  = ok ? p.c0  : 0.f; r.c1  = ok ? p.c1  : 0.f;
    return r;
}
__device__ __forceinline__ void osc_apply(const Osc& m, float& v0, float& v1) {
    const float y0 = m.a00*v0 + m.a01*v1 + m.c0;
    const float y1 = m.a10*v0 + m.a11*v1 + m.c1;
    v0 = y0; v1 = y1;
}

// ---- lower-triangular (bottom 2x2) affine scan primitives ----
struct Low { float l00, l10, l11, c0, c1; };

__device__ __forceinline__ Low low_compose(const Low& s, const Low& f) {
    Low r;
    r.l00 = s.l00*f.l00;
    r.l10 = s.l10*f.l00 + s.l11*f.l10;
    r.l11 = s.l11*f.l11;
    r.c0  = fmaf(s.l00, f.c0, s.c0);
    r.c1  = fmaf(s.l10, f.c0, fmaf(s.l11, f.c1, s.c1));
    return r;
}
__device__ __forceinline__ Low low_shfl_up(const Low& a, int d) {
    Low r;
    r.l00 = __shfl_up(a.l00, d, 64); r.l10 = __shfl_up(a.l10, d, 64);
    r.l11 = __shfl_up(a.l11, d, 64);
    r.c0  = __shfl_up(a.c0,  d, 64); r.c1  = __shfl_up(a.c1,  d, 64);
    return r;
}
__device__ __forceinline__ Low low_sel(const Low& p, bool ok) {
    Low r;
    r.l00 = ok ? p.l00 : 1.f; r.l10 = ok ? p.l10 : 0.f;
    r.l11 = ok ? p.l11 : 1.f;
    r.c0  = ok ? p.c0  : 0.f; r.c1  = ok ? p.c1  : 0.f;
    return r;
}
__device__ __forceinline__ void low_apply(const Low& m, float& x2, float& x3) {
    const float y2 = fmaf(m.l00, x2, m.c0);
    const float y3 = m.l10*x2 + m.l11*x3 + m.c1;
    x2 = y2; x3 = y3;
}

// one discretization step:
//   E = expm(M), M = balanced A*dt.
//   T block: degree-6 Taylor on M/16 in Cayley–Hamilton scalar form
//            (H = alpha*Ms + beta*I; tt = tr(Ms), dd = det(Ms));
//   C block: Horner coupled through t10 = alpha*f10, t11 = beta;
//   L block: closed form (2 exps; rates wave-uniform);
//   then 4 squarings of the full block-triangular structure.
//   G1 = phi1(M) g = M^{-1}(E - I) g   (exact identity, no series)
//   G2 = phi2(M) g = M^{-1}(G1 - g)
__device__ __forceinline__ Aff make_step(
    float Iss, float dt, float uk, float uk1,
    float rK, float AK, float tau_out, float aprod,
    float wsf, float wdf, float rwsf, float rwdf, float CWD,
    float wsfL, float wdfL)
{
    // head: wave-uniform rK = 1/(sprod*tau_out) removes both per-step frcp's
    const float a   = fmaf(tau_out, Iss, aprod) * rK;  // == (aprod/I + tau_out)*idn
    const float w2  = AK * Iss;                        // == Aloop1*idn
    const float iw  = frsq(w2);
    const float w   = w2 * iw;

    const float dts = dt * SCV;
    const float tt  = -a * dts;      // trace of Ms (= f00)
    const float f10 =  w * dts;
    const float f01 = -f10;
    const float dd  = f10 * f10;     // det of Ms = +w^2 dts^2
    const float f21 =  wsf * dts;
    const float f22 = -f21;
    const float f32 =  wdf * dts;
    const float f33 = -f32;

    // T-block Taylor deg-6 (Horner) in C-H scalar form; C-block coupled
    const float K1 = f21 * f10;
    float al = 1.0f/6.0f, be = 1.0f;
    float c00 = 0.0f, c01 = f21 * (1.0f/6.0f), c10 = 0.0f, c11 = 0.0f;
#pragma unroll
    for (int m = 5; m >= 1; --m) {
        const float rm = 1.0f / (float)m;  // folds to literal under unroll
        const float q00 = K1*al  + f22*c00;
        const float q01 = f21*be + f22*c01;
        const float q10 = f32*c00 + f33*c10;
        const float q11 = f32*c01 + f33*c11;
        const float arm = al * rm;
        const float na  = fmaf(al, tt, be) * rm;
        const float nb  = fmaf(-arm, dd, 1.0f);
        al = na; be = nb;
        c00 = q00*rm; c01 = q01*rm; c10 = q10*rm; c11 = q11*rm;
    }
    // reconstruct T entries for the ladder
    float t00 = fmaf(al, tt, be);
    float t01 = al * f01;
    float t10 = al * f10;
    float t11 = be;

    // L block closed form at base scale (exact):
    float l00 = fexp2(wsfL * dts);   // wsfL = -wsf*log2(e)
    float l11 = fexp2(wdfL * dts);
    float l10 = CWD * (l00 - l11);

    // 4 squarings of the full structure
#pragma unroll
    for (int i = 0; i < NSQ; ++i) {
        const float p00 = t00*t00 + t01*t10;
        const float p01 = t00*t01 + t01*t11;
        const float p10 = t10*t00 + t11*t10;
        const float p11 = t10*t01 + t11*t11;
        const float q00 = c00*t00 + c01*t10 + l00*c00;
        const float q01 = c00*t01 + c01*t11 + l00*c01;
        const float q10 = c10*t00 + c11*t10 + l10*c00 + l11*c10;
        const float q11 = c10*t01 + c11*t11 + l10*c01 + l11*c11;
        const float m00 = l00*l00;
        const float m10 = l10*l00 + l11*l10;
        const float m11 = l11*l11;
        t00 = p00; t01 = p01; t10 = p10; t11 = p11;
        c00 = q00; c01 = q01; c10 = q10; c11 = q11;
        l00 = m00; l10 = m10; l11 = m11;
    }

    // phi1/phi2 via exact back-substitution solves (balanced space)
    const float aw  = a * iw;           // a/w
    const float rdt = frcp(dt);
    const float rF  = iw * rdt;         // 1/(w dt)
    const float rS  = rwsf * rdt;       // 1/(wsf dt)
    const float rD  = rwdf * rdt;       // 1/(wdf dt)
    const float wS  = w * rwsf;         // w/wsf
    const float wD  = w * rwdf;         // w/wdf
    const float g0u = w * dt;

    // G1 = M^{-1}(E-I)g  (balanced)
    const float y0 = t10;
    const float y1 = -fmaf(aw, t10, t00 - 1.0f);
    const float y2 = fmaf(-wS, c00, y1);
    const float y3 = fmaf(-wD, c10, y2);
    // G2 = M^{-1}(G1 - g)  (balanced)
    const float s0 = y0 - g0u;
    const float z0 = y1 * rF;
    const float z1 = -fmaf(aw, z0, rF * s0);
    const float z2 = fmaf(-y2, rS, z1);
    const float z3 = fmaf(-y3, rD, z2);

    // unbalance: Ad = D E D^-1, D = diag(w,1,1,1); G *= D
    Aff r;
    r.a00 = t00;      r.a01 = w * t01;
    r.a10 = t10 * iw; r.a11 = t11;
    r.a20 = c00 * iw; r.a21 = c01; r.a22 = l00;
    r.a30 = c10 * iw; r.a31 = c11; r.a32 = l10; r.a33 = l11;
    const float G10 = w * y0, G20 = w * z0;
    // c = G1*uk + G2*(uk1-uk)   (== Bd*uk + Bt*uk1)
    const float du = uk1 - uk;
    r.c0 = fmaf(G10, uk, G20 * du);
    r.c1 = fmaf(y1,  uk, z1 * du);
    r.c2 = fmaf(y2,  uk, z2 * du);
    r.c3 = fmaf(y3,  uk, z3 * du);
    return r;
}

__global__ __launch_bounds__(TPB) void pbw_kernel(
    const float* __restrict__ it_eff,
    const float* __restrict__ ts,
    const float* __restrict__ p_tin_prod,
    const float* __restrict__ p_tmil_raw,
    const float* __restrict__ p_aamp_raw,
    const float* __restrict__ p_aloop_raw,
    const float* __restrict__ p_tout_raw,
    const float* __restrict__ p_tsf_raw,
    const float* __restrict__ p_tdiff_raw,
    float* __restrict__ out)
{
    __shared__ float swcA[6];       // wave-0 oscillator composite
    __shared__ float swcB[5];       // wave-0 low composite
    __shared__ float sy[SS + 4];    // output staging (+4 pad for tail thread)

    const int b = blockIdx.x;
    const int t = threadIdx.x;
    const int lane = t & 63;
    const int wv = t >> 6;

    // derived scalar params (wave-uniform)
    const float tin_prod  = p_tin_prod[0];
    const float tmil_prod = log1pf(expf(p_tmil_raw[0]));
    const float Aamp1     = 1.0f / log1pf(expf(p_aamp_raw[0])) + 1.0f;
    const float Aloop1    = 1.0f / log1pf(expf(p_aloop_raw[0])) + 1.0f;
    const float tau_out   = log1pf(expf(p_tout_raw[0]));
    const float sp_sf     = log1pf(expf(p_tsf_raw[0]));
    const float sp_df     = log1pf(expf(p_tdiff_raw[0]));
    const float wsf       = 1.0f / sp_sf;
    const float wdf       = 1.0f / sp_df;
    const float CWD       = wdf / (wdf - wsf);            // wave-uniform
    const float sprod = tin_prod + tmil_prod;             // (tin+tml)*I
    const float aprod = fmaf(Aamp1, tmil_prod, tin_prod); // (tin+Aamp1*tml)*I
    const float rK    = 1.0f / (sprod * tau_out);         // idn = I*rK
    const float AK    = Aloop1 * rK;                      // w2 = AK*I
    const float wsfL  = -wsf * LOG2E;                     // exp2 constants
    const float wdfL  = -wdf * LOG2E;

    const float* rowI = it_eff + (size_t)b * SS;
    const float* rowT = ts     + (size_t)b * SS;

    // thread t owns steps k = 4t .. 4t+3 (last thread: 3 real + identity)
    const int k0 = 4 * t;
    const float4 I4 = *(const float4*)(rowI + k0);
    const float4 T4 = *(const float4*)(rowT + k0);
    const bool last = (t == TPB - 1);
    const float I_4 = last ? 1.0f : rowI[k0 + 4];
    const float T_4 = last ? (T4.w + 1e-4f) : rowT[k0 + 4];

    const float u_0 = flog(I4.x);
    const float u_1 = flog(I4.y);
    const float u_2 = flog(I4.z);
    const float u_3 = flog(I4.w);
    const float u_4 = flog(I_4);
    const float u0  = flog(rowI[0]);   // broadcast load

    Aff m0 = make_step(I4.y, T4.y - T4.x, u_0, u_1,
                       rK, AK, tau_out, aprod, wsf, wdf, sp_sf, sp_df, CWD,
                       wsfL, wdfL);
    Aff m1 = make_step(I4.z, T4.z - T4.y, u_1, u_2,
                       rK, AK, tau_out, aprod, wsf, wdf, sp_sf, sp_df, CWD,
                       wsfL, wdfL);
    Aff m2 = make_step(I4.w, T4.w - T4.z, u_2, u_3,
                       rK, AK, tau_out, aprod, wsf, wdf, sp_sf, sp_df, CWD,
                       wsfL, wdfL);
    Aff m3 = make_step(I_4, T_4 - T4.w, u_3, u_4,
                       rK, AK, tau_out, aprod, wsf, wdf, sp_sf, sp_df, CWD,
                       wsfL, wdfL);
    if (last) m3 = aff_identity();

    // ================= Phase A: oscillator (x0,x1) scan =================
    const Osc s0 = {m0.a00, m0.a01, m0.a10, m0.a11, m0.c0, m0.c1};
    const Osc s1 = {m1.a00, m1.a01, m1.a10, m1.a11, m1.c0, m1.c1};
    const Osc s2 = {m2.a00, m2.a01, m2.a10, m2.a11, m2.c0, m2.c1};
    const Osc s3 = {m3.a00, m3.a01, m3.a10, m3.a11, m3.c0, m3.c1};

    Osc oc = osc_compose(osc_compose(s3, s2), osc_compose(s1, s0));
#pragma unroll
    for (int d = 1; d < 64; d <<= 1) {
        Osc p = osc_shfl_up(oc, d);
        p = osc_sel(p, lane >= d);
        oc = osc_compose(oc, p);
    }
    if (wv == 0 && lane == 63) {
        swcA[0]=oc.a00; swcA[1]=oc.a01; swcA[2]=oc.a10; swcA[3]=oc.a11;
        swcA[4]=oc.c0;  swcA[5]=oc.c1;
    }
    __syncthreads();

    float v0 = 0.0f, v1 = u0;
    if (wv == 1) {
        Osc wm = {swcA[0], swcA[1], swcA[2], swcA[3], swcA[4], swcA[5]};
        osc_apply(wm, v0, v1);
    }
    Osc oex = osc_shfl_up(oc, 1);
    oex = osc_sel(oex, lane >= 1);
    osc_apply(oex, v0, v1);

    // v at the 4 local step-starts
    const float va0 = v0, vb0 = v1;
    osc_apply(s0, v0, v1); const float va1 = v0, vb1 = v1;
    osc_apply(s1, v0, v1); const float va2 = v0, vb2 = v1;
    osc_apply(s2, v0, v1); const float va3 = v0, vb3 = v1;

    // ================= Phase B: lower-tri (x2,x3) scan =================
    const Low b0 = {m0.a22, m0.a32, m0.a33,
                    m0.a20*va0 + m0.a21*vb0 + m0.c2,
                    m0.a30*va0 + m0.a31*vb0 + m0.c3};
    const Low b1 = {m1.a22, m1.a32, m1.a33,
                    m1.a20*va1 + m1.a21*vb1 + m1.c2,
                    m1.a30*va1 + m1.a31*vb1 + m1.c3};
    const Low b2 = {m2.a22, m2.a32, m2.a33,
                    m2.a20*va2 + m2.a21*vb2 + m2.c2,
                    m2.a30*va2 + m2.a31*vb2 + m2.c3};
    const Low b3 = {m3.a22, m3.a32, m3.a33,
                    m3.a20*va3 + m3.a21*vb3 + m3.c2,
                    m3.a30*va3 + m3.a31*vb3 + m3.c3};

    Low lc = low_compose(low_compose(b3, b2), low_compose(b1, b0));
#pragma unroll
    for (int d = 1; d < 64; d <<= 1) {
        Low p = low_shfl_up(lc, d);
        p = low_sel(p, lane >= d);
        lc = low_compose(lc, p);
    }
    if (wv == 0 && lane == 63) {
        swcB[0]=lc.l00; swcB[1]=lc.l10; swcB[2]=lc.l11;
        swcB[3]=lc.c0;  swcB[4]=lc.c1;
    }
    __syncthreads();

    float x2 = u0, x3 = u0;
    if (wv == 1) {
        Low wm = {swcB[0], swcB[1], swcB[2], swcB[3], swcB[4]};
        low_apply(wm, x2, x3);
    }
    Low lex = low_shfl_up(lc, 1);
    lex = low_sel(lex, lane >= 1);
    low_apply(lex, x2, x3);

    // replay: y = x3 after each local step
    low_apply(b0, x2, x3); sy[k0 + 1] = x3;
    low_apply(b1, x2, x3); sy[k0 + 2] = x3;
    low_apply(b2, x2, x3); sy[k0 + 3] = x3;
    low_apply(b3, x2, x3); sy[k0 + 4] = x3;   // k0+4==512 lands in pad
    if (t == 0) sy[0] = u0;

    __syncthreads();

    // coalesced float4 store
    float4* po = (float4*)(out + (size_t)b * SS);
    po[t] = *(const float4*)&sy[4 * t];
}

extern "C" void kernel_launch(void* const* d_in, const int* in_sizes, int n_in,
                              void* d_out, int out_size, void* d_ws, size_t ws_size,
                              hipStream_t stream) {
    const float* it_eff = (const float*)d_in[0];
    const float* ts     = (const float*)d_in[1];
    const float* p2 = (const float*)d_in[2];
    const float* p3 = (const float*)d_in[3];
    const float* p4 = (const float*)d_in[4];
    const float* p5 = (const float*)d_in[5];
    const float* p6 = (const float*)d_in[6];
    const float* p7 = (const float*)d_in[7];
    const float* p8 = (const float*)d_in[8];
    float* out = (float*)d_out;

    pbw_kernel<<<dim3(BB), dim3(TPB), 0, stream>>>(
        it_eff, ts, p2, p3, p4, p5, p6, p7, p8, out);
}